// Round 8
// baseline (307.858 us; speedup 1.0000x reference)
//
#include <hip/hip_runtime.h>

// GNNTimeModel: X[B,V,T], A[T,V,V], W[F,1] -> out[B,T,V*F]
// B=64 V=64 T=256 F=64. Output = 256 MiB f32, written once -> HBM-write-bound.
#define BB 64
#define VV 64
#define TT 256
#define FF 64
constexpr float NEG_SLOPE = 0.01f;

// ---------------------------------------------------------------------------
// Kernel 1: one block per t. Computes adj_t = sigmoid(A[t]) (diag forced 1)
// ONCE per t (fused version recomputed it 64x), then the V x V matvec against
// X[b,:,t] for all 64 b's. Writes H[(b*T+t)*V + v] (4 MiB) into d_ws, laid
// out to match the output ordering so kernel 2's reads are coalesced.
// ---------------------------------------------------------------------------
__global__ __launch_bounds__(256) void gnn_agg(
    const float* __restrict__ X,
    const float* __restrict__ A,
    float* __restrict__ H)
{
    __shared__ float adjS[VV][VV + 1];  // +1 pad: column reads -> 2-way (free)
    __shared__ float xsS[VV][VV + 1];   // xsS[b][w] = X[b, w, t]

    const int tid = threadIdx.x;
    const int t = blockIdx.x;

    // stage sigmoid(A[t]) -> LDS (coalesced 1 KiB/wave reads)
    const float* At = A + (size_t)t * (VV * VV);
    #pragma unroll
    for (int i = 0; i < (VV * VV) / 256; ++i) {
        int idx = i * 256 + tid;
        int v = idx >> 6;
        int w = idx & 63;
        float a = At[idx];
        float s = 1.0f / (1.0f + __expf(-a));
        adjS[v][w] = (v == w) ? 1.0f : s;
    }

    // stage X[:, :, t] -> LDS (strided 4B reads; X is 4 MiB, L2/L3-resident)
    #pragma unroll
    for (int i = 0; i < (VV * VV) / 256; ++i) {
        int idx = i * 256 + tid;
        int b = idx >> 6;       // wave-uniform
        int w = idx & 63;       // = lane -> contiguous LDS write
        xsS[b][w] = X[(size_t)b * (VV * TT) + (size_t)w * TT + t];
    }
    __syncthreads();

    // matvec: H[b,t,v] = sum_w adjS[v][w] * xsS[b][w]; 16 outputs/thread.
    // Per wave-instr: v = lane (adjS column read, 2-way = free),
    //                 b wave-uniform (xsS read is an LDS broadcast).
    #pragma unroll
    for (int i = 0; i < 16; ++i) {
        int flat = i * 256 + tid;
        int b = flat >> 6;
        int v = flat & 63;
        float sum = 0.0f;
        #pragma unroll
        for (int w = 0; w < VV; ++w) {
            sum += adjS[v][w] * xsS[b][w];
        }
        // contiguous 256 B store per wave-instr
        H[(size_t)b * (TT * VV) + (size_t)t * VV + v] = sum;
    }
}

// ---------------------------------------------------------------------------
// Kernel 2: pure streaming expansion — structurally a fillBuffer plus one
// broadcast multiply. One block per 4096-float output chunk (= 64 h values).
// out[b,t,v,f] = leaky(H[b,t,v] * W[f]); 16 KiB contiguous float4 per block.
// ---------------------------------------------------------------------------
__global__ __launch_bounds__(256) void gnn_expand(
    const float* __restrict__ H,
    const float* __restrict__ W,
    float* __restrict__ out)
{
    __shared__ float hs[VV];

    const int tid = threadIdx.x;
    const int bid = blockIdx.x;   // = b*T + t

    if (tid < VV) {
        hs[tid] = H[(size_t)bid * VV + tid];  // 256 B coalesced
    }
    // per-thread W fragment is loop-invariant: (4*idx4) & 63 == (4*tid) & 63
    const float4 w4 = *reinterpret_cast<const float4*>(W + ((4 * tid) & 63));
    __syncthreads();

    float4* out4 = reinterpret_cast<float4*>(out + (size_t)bid * (VV * FF));
    #pragma unroll
    for (int k = 0; k < 4; ++k) {
        int idx4 = k * 256 + tid;             // lanes contiguous -> 1 KiB/instr
        float h = hs[idx4 >> 4];              // 16 lanes share: LDS broadcast
        float4 r;
        r.x = h * w4.x;
        r.y = h * w4.y;
        r.z = h * w4.z;
        r.w = h * w4.w;
        r.x = (r.x >= 0.0f) ? r.x : NEG_SLOPE * r.x;
        r.y = (r.y >= 0.0f) ? r.y : NEG_SLOPE * r.y;
        r.z = (r.z >= 0.0f) ? r.z : NEG_SLOPE * r.z;
        r.w = (r.w >= 0.0f) ? r.w : NEG_SLOPE * r.w;
        out4[idx4] = r;
    }
}

extern "C" void kernel_launch(void* const* d_in, const int* in_sizes, int n_in,
                              void* d_out, int out_size, void* d_ws, size_t ws_size,
                              hipStream_t stream) {
    const float* X = (const float*)d_in[0];
    const float* A = (const float*)d_in[1];
    const float* W = (const float*)d_in[2];
    float* out = (float*)d_out;
    float* H = (float*)d_ws;   // 4 MiB scratch: H_agg in (b*T+t)*V + v layout

    gnn_agg<<<TT, 256, 0, stream>>>(X, A, H);
    gnn_expand<<<BB * TT, 256, 0, stream>>>(H, W, out);
}

// Round 9
// 304.338 us; speedup vs baseline: 1.0116x; 1.0116x over previous
//
#include <hip/hip_runtime.h>

// GNNTimeModel: X[B,V,T], A[T,V,V], W[F,1] -> out[B,T,V*F]
// B=64 V=64 T=256 F=64. Output = 256 MiB f32, written once -> HBM-write-bound.
#define BB 64
#define VV 64
#define TT 256
#define FF 64
constexpr float NEG_SLOPE = 0.01f;

// ---------------------------------------------------------------------------
// Kernel 1: one block per t. adj_t = sigmoid(A[t]) (diag=1) computed once per
// t, then the V x V matvec against X[b,:,t] for all 64 b. Writes H (4 MiB)
// to d_ws in (b*T+t)*V + v layout (matches output ordering).
// ---------------------------------------------------------------------------
__global__ __launch_bounds__(256) void gnn_agg(
    const float* __restrict__ X,
    const float* __restrict__ A,
    float* __restrict__ H)
{
    __shared__ float adjS[VV][VV + 1];  // +1 pad: column reads -> 2-way (free)
    __shared__ float xsS[VV][VV + 1];   // xsS[b][w] = X[b, w, t]

    const int tid = threadIdx.x;
    const int t = blockIdx.x;

    const float* At = A + (size_t)t * (VV * VV);
    #pragma unroll
    for (int i = 0; i < (VV * VV) / 256; ++i) {
        int idx = i * 256 + tid;
        int v = idx >> 6;
        int w = idx & 63;
        float a = At[idx];
        float s = 1.0f / (1.0f + __expf(-a));
        adjS[v][w] = (v == w) ? 1.0f : s;
    }

    #pragma unroll
    for (int i = 0; i < (VV * VV) / 256; ++i) {
        int idx = i * 256 + tid;
        int b = idx >> 6;       // wave-uniform
        int w = idx & 63;       // = lane -> contiguous LDS write
        xsS[b][w] = X[(size_t)b * (VV * TT) + (size_t)w * TT + t];
    }
    __syncthreads();

    #pragma unroll
    for (int i = 0; i < 16; ++i) {
        int flat = i * 256 + tid;
        int b = flat >> 6;
        int v = flat & 63;
        float sum = 0.0f;
        #pragma unroll
        for (int w = 0; w < VV; ++w) {
            sum += adjS[v][w] * xsS[b][w];
        }
        H[(size_t)b * (TT * VV) + (size_t)t * VV + v] = sum;
    }
}

// ---------------------------------------------------------------------------
// Kernel 2 (v2): pure streamer. No LDS, no barrier. 2048 blocks x 8 chunks
// (chunk = one (b,t) = 4096 floats). Each h value is shared by 16 lanes ->
// direct global broadcast load (one 64B line per wave-instr). All 32 h-loads
// hoisted to registers up front (static indices, full unroll), then an
// uninterrupted 128 KiB contiguous float4 store stream per block.
// ---------------------------------------------------------------------------
#define CHUNKS_PER_BLOCK 8
__global__ __launch_bounds__(256) void gnn_expand(
    const float* __restrict__ H,
    const float* __restrict__ W,
    float* __restrict__ out)
{
    const int tid = threadIdx.x;
    const int c0 = blockIdx.x * CHUNKS_PER_BLOCK;   // first (b*T+t) chunk

    // per-thread W fragment, loop-invariant: (4*(k*256+tid)) & 63 == (4*tid)&63
    const float4 w4 = *reinterpret_cast<const float4*>(W + ((4 * tid) & 63));
    const int sub = tid >> 4;   // which h in each 16-lane group

    // hoist all h loads: hv[j][k] = H[(c0+j)*64 + k*16 + sub]
    float hv[CHUNKS_PER_BLOCK][4];
    #pragma unroll
    for (int j = 0; j < CHUNKS_PER_BLOCK; ++j) {
        #pragma unroll
        for (int k = 0; k < 4; ++k) {
            hv[j][k] = H[(size_t)(c0 + j) * VV + k * 16 + sub];
        }
    }

    float4* out4 = reinterpret_cast<float4*>(out + (size_t)c0 * (VV * FF));
    #pragma unroll
    for (int j = 0; j < CHUNKS_PER_BLOCK; ++j) {
        #pragma unroll
        for (int k = 0; k < 4; ++k) {
            float h = hv[j][k];
            float4 r;
            r.x = h * w4.x;
            r.y = h * w4.y;
            r.z = h * w4.z;
            r.w = h * w4.w;
            r.x = (r.x >= 0.0f) ? r.x : NEG_SLOPE * r.x;
            r.y = (r.y >= 0.0f) ? r.y : NEG_SLOPE * r.y;
            r.z = (r.z >= 0.0f) ? r.z : NEG_SLOPE * r.z;
            r.w = (r.w >= 0.0f) ? r.w : NEG_SLOPE * r.w;
            out4[j * 1024 + k * 256 + tid] = r;   // 1 KiB contiguous per wave
        }
    }
}

extern "C" void kernel_launch(void* const* d_in, const int* in_sizes, int n_in,
                              void* d_out, int out_size, void* d_ws, size_t ws_size,
                              hipStream_t stream) {
    const float* X = (const float*)d_in[0];
    const float* A = (const float*)d_in[1];
    const float* W = (const float*)d_in[2];
    float* out = (float*)d_out;
    float* H = (float*)d_ws;   // 4 MiB scratch: H_agg in (b*T+t)*V + v layout

    gnn_agg<<<TT, 256, 0, stream>>>(X, A, H);
    gnn_expand<<<(BB * TT) / CHUNKS_PER_BLOCK, 256, 0, stream>>>(H, W, out);
}

// Round 12
// 290.875 us; speedup vs baseline: 1.0584x; 1.0463x over previous
//
#include <hip/hip_runtime.h>

// GNNTimeModel: X[B,V,T], A[T,V,V], W[F,1] -> out[B,T,V*F]
// B=64 V=64 T=256 F=64. Output = 256 MiB f32, written once -> HBM-write-bound.
#define BB 64
#define VV 64
#define TT 256
#define FF 64
constexpr float NEG_SLOPE = 0.01f;

// ---------------------------------------------------------------------------
// Kernel 1 (v3): one block per t. Register-blocked matvec.
//   wave w_id owns b in [w_id*16, w_id*16+16); lane owns v = lane.
//   Per w-step: 1 adjS b32 read (2-way, free) + 4 same-address float4
//   broadcasts of xsT[w] + 16 FMAs into acc[16] registers.
//   LDS instrs/thread: 64 + 256 (was 2048 b32 in v1/v2 -> the ~40us culprit).
// ---------------------------------------------------------------------------
__global__ __launch_bounds__(256) void gnn_agg(
    const float* __restrict__ X,
    const float* __restrict__ A,
    float* __restrict__ H)
{
    __shared__ float adjS[VV][VV + 1];  // stride 65: (v+w)%32 -> 2-way = free
    __shared__ float xsT[VV][VV];       // xsT[w][b]; b=lane on write -> free

    const int tid = threadIdx.x;
    const int t = blockIdx.x;

    // stage sigmoid(A[t]) (diag=1), coalesced 1 KiB/wave reads
    const float* At = A + (size_t)t * (VV * VV);
    #pragma unroll
    for (int i = 0; i < (VV * VV) / 256; ++i) {
        int idx = i * 256 + tid;
        int v = idx >> 6;
        int w = idx & 63;
        float a = At[idx];
        float s = 1.0f / (1.0f + __expf(-a));
        adjS[v][w] = (v == w) ? 1.0f : s;
    }

    // stage X[:, :, t] transposed: xsT[w][b] = X[b, w, t]
    // (b = lane: global reads scattered -- unavoidable for a t-column of
    //  [B,V,T]; only 64 KiB of lines per block, L2-shared across 16 t's)
    #pragma unroll
    for (int i = 0; i < (VV * VV) / 256; ++i) {
        int idx = i * 256 + tid;
        int w = idx >> 6;       // wave-uniform
        int b = idx & 63;       // = lane -> contiguous LDS write, 2-way free
        xsT[w][b] = X[((size_t)b * VV + w) * TT + t];
    }
    __syncthreads();

    // register-blocked matvec: acc[j] = H[b0+j, t, v], v = lane
    const int v = tid & 63;
    const int b0 = (tid >> 6) * 16;   // wave's b-range
    float acc[16];
    #pragma unroll
    for (int j = 0; j < 16; ++j) acc[j] = 0.0f;

    const float4* xrow;
    #pragma unroll 4
    for (int w = 0; w < VV; ++w) {
        float a = adjS[v][w];
        xrow = reinterpret_cast<const float4*>(&xsT[w][b0]);
        float4 x0 = xrow[0];   // same-address across wave: LDS broadcast
        float4 x1 = xrow[1];
        float4 x2 = xrow[2];
        float4 x3 = xrow[3];
        acc[0]  += a * x0.x;  acc[1]  += a * x0.y;
        acc[2]  += a * x0.z;  acc[3]  += a * x0.w;
        acc[4]  += a * x1.x;  acc[5]  += a * x1.y;
        acc[6]  += a * x1.z;  acc[7]  += a * x1.w;
        acc[8]  += a * x2.x;  acc[9]  += a * x2.y;
        acc[10] += a * x2.z;  acc[11] += a * x2.w;
        acc[12] += a * x3.x;  acc[13] += a * x3.y;
        acc[14] += a * x3.z;  acc[15] += a * x3.w;
    }

    // store: lane-contiguous 256 B per wave-instr, 16 instrs
    #pragma unroll
    for (int j = 0; j < 16; ++j) {
        int b = b0 + j;
        H[((size_t)b * TT + t) * VV + v] = acc[j];
    }
}

// ---------------------------------------------------------------------------
// Kernel 2 (unchanged v2): pure streamer at fill-BW floor. No LDS/barrier.
// 2048 blocks x 8 chunks; h values via 16-lane same-address global broadcast;
// 128 KiB contiguous float4 store stream per block.
// ---------------------------------------------------------------------------
#define CHUNKS_PER_BLOCK 8
__global__ __launch_bounds__(256) void gnn_expand(
    const float* __restrict__ H,
    const float* __restrict__ W,
    float* __restrict__ out)
{
    const int tid = threadIdx.x;
    const int c0 = blockIdx.x * CHUNKS_PER_BLOCK;   // first (b*T+t) chunk

    const float4 w4 = *reinterpret_cast<const float4*>(W + ((4 * tid) & 63));
    const int sub = tid >> 4;   // which h in each 16-lane group

    float hv[CHUNKS_PER_BLOCK][4];
    #pragma unroll
    for (int j = 0; j < CHUNKS_PER_BLOCK; ++j) {
        #pragma unroll
        for (int k = 0; k < 4; ++k) {
            hv[j][k] = H[(size_t)(c0 + j) * VV + k * 16 + sub];
        }
    }

    float4* out4 = reinterpret_cast<float4*>(out + (size_t)c0 * (VV * FF));
    #pragma unroll
    for (int j = 0; j < CHUNKS_PER_BLOCK; ++j) {
        #pragma unroll
        for (int k = 0; k < 4; ++k) {
            float h = hv[j][k];
            float4 r;
            r.x = h * w4.x;
            r.y = h * w4.y;
            r.z = h * w4.z;
            r.w = h * w4.w;
            r.x = (r.x >= 0.0f) ? r.x : NEG_SLOPE * r.x;
            r.y = (r.y >= 0.0f) ? r.y : NEG_SLOPE * r.y;
            r.z = (r.z >= 0.0f) ? r.z : NEG_SLOPE * r.z;
            r.w = (r.w >= 0.0f) ? r.w : NEG_SLOPE * r.w;
            out4[j * 1024 + k * 256 + tid] = r;   // 1 KiB contiguous per wave
        }
    }
}

extern "C" void kernel_launch(void* const* d_in, const int* in_sizes, int n_in,
                              void* d_out, int out_size, void* d_ws, size_t ws_size,
                              hipStream_t stream) {
    const float* X = (const float*)d_in[0];
    const float* A = (const float*)d_in[1];
    const float* W = (const float*)d_in[2];
    float* out = (float*)d_out;
    float* H = (float*)d_ws;   // 4 MiB scratch: H_agg in (b*T+t)*V + v layout

    gnn_agg<<<TT, 256, 0, stream>>>(X, A, H);
    gnn_expand<<<(BB * TT) / CHUNKS_PER_BLOCK, 256, 0, stream>>>(H, W, out);
}